// Round 1
// 1207.355 us; speedup vs baseline: 1.0825x; 1.0825x over previous
//
#include <hip/hip_runtime.h>

// ---------------- types & helpers ----------------
typedef __bf16 bf16x8 __attribute__((ext_vector_type(8)));
typedef float  f32x4  __attribute__((ext_vector_type(4)));

__device__ __forceinline__ unsigned short f2bf(float f) {
    unsigned u = __float_as_uint(f);
    u += 0x7fffu + ((u >> 16) & 1u);   // RNE
    return (unsigned short)(u >> 16);
}

__device__ __forceinline__ void gld_lds16(const void* g, void* l) {
    __builtin_amdgcn_global_load_lds(
        (const __attribute__((address_space(1))) void*)g,
        (__attribute__((address_space(3))) void*)l,
        16, 0, 0);
}

#define WAITVM(N) asm volatile("s_waitcnt vmcnt(" #N ")" ::: "memory")

// ---------------- problem constants ----------------
#define NB  32
#define SQ  256
#define HD  1024
#define ID  4096
#define NEXP 8          // skill experts; index 8 = shared
#define PAIRS (NB * 3)  // (batch, slot) pairs

// workspace layout (bytes)
#define OFF_EID    ((size_t)0)            // 96 int
#define OFF_WGT    ((size_t)512)          // 96 float
#define OFF_XBF    ((size_t)1024)                       // 8192*1024 bf16
#define OFF_GATET  (OFF_XBF   + (size_t)16777216)       // 9*4096*1024 bf16
#define OFF_UPT    (OFF_GATET + (size_t)75497472)
#define OFF_DOWNT  (OFF_UPT   + (size_t)75497472)
#define OFF_ACT    (OFF_DOWNT + (size_t)75497472)       // 96*256*4096 bf16

// ---------------- routing ----------------
__global__ void routing_kernel(const float* __restrict__ logits,
                               int* __restrict__ eid, float* __restrict__ wgt) {
    int b = threadIdx.x;
    if (b < NB) {
        float l[NEXP];
        for (int j = 0; j < NEXP; ++j) l[j] = logits[b * NEXP + j];
        int a0 = 0;
        for (int j = 1; j < NEXP; ++j) if (l[j] > l[a0]) a0 = j;
        int a1 = -1;
        for (int j = 0; j < NEXP; ++j) {
            if (j == a0) continue;
            if (a1 < 0 || l[j] > l[a1]) a1 = j;
        }
        float w0 = 1.0f / (1.0f + expf(l[a1] - l[a0]));
        eid[b * 3 + 0] = a0;  wgt[b * 3 + 0] = w0;
        eid[b * 3 + 1] = a1;  wgt[b * 3 + 1] = 1.0f - w0;
        eid[b * 3 + 2] = NEXP; wgt[b * 3 + 2] = 1.0f;   // shared
    }
}

// ---------------- x fp32 -> bf16 ----------------
__global__ void xcvt_kernel(const float* __restrict__ x,
                            unsigned short* __restrict__ xb, int n4) {
    int i = blockIdx.x * 256 + threadIdx.x;
    if (i < n4) {
        float4 v = ((const float4*)x)[i];
        union { unsigned short s[4]; uint2 u; } p;
        p.s[0] = f2bf(v.x); p.s[1] = f2bf(v.y);
        p.s[2] = f2bf(v.z); p.s[3] = f2bf(v.w);
        ((uint2*)xb)[i] = p.u;
    }
}

// ---------------- weight transpose+convert: [R][C] fp32 -> [C][R] bf16 ----------------
__global__ void transpose_cvt(const float* __restrict__ skill,
                              const float* __restrict__ shared_m,
                              unsigned short* __restrict__ out, int R, int C) {
    const int e = blockIdx.z;                       // 0..8
    const float* src = (e < NEXP) ? (skill + (size_t)e * R * C) : shared_m;
    unsigned short* dst = out + (size_t)e * R * C;  // [C][R]
    const int c0 = blockIdx.x * 64;
    const int r0 = blockIdx.y * 64;
    __shared__ unsigned short t[64][66];
    const int tid = threadIdx.x;
    const int lr = tid >> 4;            // 0..15
    const int lc = (tid & 15) * 4;
    for (int it = 0; it < 4; ++it) {
        int r = lr + it * 16;
        float4 v = *(const float4*)(src + (size_t)(r0 + r) * C + c0 + lc);
        t[r][lc + 0] = f2bf(v.x);
        t[r][lc + 1] = f2bf(v.y);
        t[r][lc + 2] = f2bf(v.z);
        t[r][lc + 3] = f2bf(v.w);
    }
    __syncthreads();
    const int oc = tid >> 2;            // out row (original col), 0..63
    const int k0 = (tid & 3) * 16;      // 16 elems along original rows
    unsigned int pk[8];
    for (int j = 0; j < 8; ++j) {
        unsigned int lo = t[k0 + 2 * j + 0][oc];
        unsigned int hi = t[k0 + 2 * j + 1][oc];
        pk[j] = lo | (hi << 16);
    }
    unsigned short* dp = dst + (size_t)(c0 + oc) * R + r0 + k0;
    ((uint4*)dp)[0] = make_uint4(pk[0], pk[1], pk[2], pk[3]);
    ((uint4*)dp)[1] = make_uint4(pk[4], pk[5], pk[6], pk[7]);
}

// =====================================================================
// stage1: act = gelu(x@gate) * (x@up) * w  (bf16 out)
// 512 thr / 8 waves, tile M128 x N128(gate)+N128(up), BK=64.
// Triple-buffered LDS (distance-2 prefetch), counted vmcnt, 2 lockstep
// phases per K-tile, XOR-swizzled LDS (pre-swizzled global source).
// =====================================================================
__global__ __launch_bounds__(512, 2) void stage1_gateup(
    const unsigned short* __restrict__ xbf,     // [8192][1024]
    const unsigned short* __restrict__ gateT,   // [9][4096][1024]
    const unsigned short* __restrict__ upT,
    const int* __restrict__ eid, const float* __restrict__ wgt,
    unsigned short* __restrict__ act)           // [96][256][4096]
{
    extern __shared__ unsigned short lds[];     // 3 bufs * 24576 shorts (144 KiB)

    // bijective XCD-chunked swizzle: 6144 = 8 * 768
    const int lid = blockIdx.x;
    const int swz = (lid & 7) * 768 + (lid >> 3);
    const int nt  = swz & 31;          // I tile
    const int mt  = (swz >> 5) & 1;    // token tile
    const int p   = swz >> 6;          // (b,slot) pair
    const int b   = p / 3;
    const int e   = eid[p];
    const float wS = wgt[p];

    const int tid  = threadIdx.x;
    const int wv   = tid >> 6;
    const int lane = tid & 63;
    const int wr   = wv >> 2;          // 0..1 : M half
    const int wc   = wv & 3;           // 0..3 : N quarter

    // staging lane geometry: seg = 8 rows x 64 cols (1 KiB); lane l -> row lhi, chunk llo.
    // Pre-swizzle SOURCE chunk (llo ^ lhi); LDS dest stays linear (gld_lds requirement).
    const int lhi  = lane >> 3;
    const int llo  = lane & 7;
    const int csw8 = (llo ^ lhi) * 8;
    const int w2   = wv * 2;

    const size_t lofs = (size_t)(wv * 16 + lhi) * HD + csw8;
    const unsigned short* pA = xbf   + (size_t)(b * SQ + mt * 128) * HD + lofs;
    const unsigned short* pG = gateT + ((size_t)e * ID + nt * 128) * HD + lofs;
    const unsigned short* pU = upT   + ((size_t)e * ID + nt * 128) * HD + lofs;

    // read-side: row&7 == lrow&7 (mf*16 = 0 mod 8) -> per-thread constant XOR
    const int lrow = lane & 15;
    const int kq   = (lane >> 4) * 8;
    const int xt   = (lrow & 7) << 3;
    const int c0s  = kq ^ xt;          // phase 1 (kk=0)  swizzled col offset
    const int c1s  = (32 + kq) ^ xt;   // phase 2 (kk=32)
    const int rA0  = (wr * 64 + lrow) * 64;
    const int rG0  = (wc * 32 + lrow) * 64;

    f32x4 accg[4][2], accu[4][2];
#pragma unroll
    for (int i = 0; i < 4; ++i)
#pragma unroll
        for (int j = 0; j < 2; ++j) { accg[i][j] = (f32x4)0.f; accu[i][j] = (f32x4)0.f; }

    const int NT = HD / 64;   // 16 K-tiles

    // prologue: stage tiles 0,1 into bufs 0,1 (12 loads/thread outstanding)
#pragma unroll
    for (int t0 = 0; t0 < 2; ++t0) {
        unsigned short* Lb = lds + t0 * 24576;
#pragma unroll
        for (int q = 0; q < 2; ++q) {
            const size_t o = (size_t)t0 * 64 + (size_t)q * (8 * HD);
            gld_lds16(pA + o, Lb +         (w2 + q) * 512);
            gld_lds16(pG + o, Lb +  8192 + (w2 + q) * 512);
            gld_lds16(pU + o, Lb + 16384 + (w2 + q) * 512);
        }
    }

    int cur = 0, tgt = 2;
#pragma unroll 1
    for (int t = 0; t < NT; ++t) {
        __builtin_amdgcn_sched_barrier(0);   // pin: no staging hoists across prev end-of-tile barrier
        unsigned short* Lc = lds + cur * 24576;
        unsigned short* Lt = lds + tgt * 24576;
        const bool pf = (t + 2 < NT);
        const size_t kp = (size_t)(t + 2) * 64;
        if (pf) {
            // first half of distance-2 prefetch, issued BEFORE the counted wait
            gld_lds16(pA + kp, Lt +         w2 * 512);
            gld_lds16(pG + kp, Lt +  8192 + w2 * 512);
            gld_lds16(pU + kp, Lt + 16384 + w2 * 512);
            WAITVM(9);                 // leave t+1's 6 + t+2's 3 in flight; t's staging done
        } else if (t + 1 < NT) {
            WAITVM(6);
        } else {
            WAITVM(0);
        }
        __builtin_amdgcn_s_barrier();
        __builtin_amdgcn_sched_barrier(0);

        // ---- phase 1: kk = 0 ----
        {
            bf16x8 af[4], gf[2], uf[2];
#pragma unroll
            for (int mf = 0; mf < 4; ++mf)
                af[mf] = *(const bf16x8*)(Lc + rA0 + mf * 1024 + c0s);
#pragma unroll
            for (int nf = 0; nf < 2; ++nf) {
                gf[nf] = *(const bf16x8*)(Lc +  8192 + rG0 + nf * 1024 + c0s);
                uf[nf] = *(const bf16x8*)(Lc + 16384 + rG0 + nf * 1024 + c0s);
            }
            __builtin_amdgcn_s_setprio(1);
#pragma unroll
            for (int mf = 0; mf < 4; ++mf)
#pragma unroll
                for (int nf = 0; nf < 2; ++nf) {
                    accg[mf][nf] = __builtin_amdgcn_mfma_f32_16x16x32_bf16(af[mf], gf[nf], accg[mf][nf], 0, 0, 0);
                    accu[mf][nf] = __builtin_amdgcn_mfma_f32_16x16x32_bf16(af[mf], uf[nf], accu[mf][nf], 0, 0, 0);
                }
            __builtin_amdgcn_s_setprio(0);
        }
        __builtin_amdgcn_s_barrier();

        // ---- phase 2: kk = 32 (+ second half of prefetch) ----
        {
            bf16x8 af[4], gf[2], uf[2];
#pragma unroll
            for (int mf = 0; mf < 4; ++mf)
                af[mf] = *(const bf16x8*)(Lc + rA0 + mf * 1024 + c1s);
#pragma unroll
            for (int nf = 0; nf < 2; ++nf) {
                gf[nf] = *(const bf16x8*)(Lc +  8192 + rG0 + nf * 1024 + c1s);
                uf[nf] = *(const bf16x8*)(Lc + 16384 + rG0 + nf * 1024 + c1s);
            }
            if (pf) {
                gld_lds16(pA + kp + 8 * HD, Lt +         (w2 + 1) * 512);
                gld_lds16(pG + kp + 8 * HD, Lt +  8192 + (w2 + 1) * 512);
                gld_lds16(pU + kp + 8 * HD, Lt + 16384 + (w2 + 1) * 512);
            }
            __builtin_amdgcn_s_setprio(1);
#pragma unroll
            for (int mf = 0; mf < 4; ++mf)
#pragma unroll
                for (int nf = 0; nf < 2; ++nf) {
                    accg[mf][nf] = __builtin_amdgcn_mfma_f32_16x16x32_bf16(af[mf], gf[nf], accg[mf][nf], 0, 0, 0);
                    accu[mf][nf] = __builtin_amdgcn_mfma_f32_16x16x32_bf16(af[mf], uf[nf], accu[mf][nf], 0, 0, 0);
                }
            __builtin_amdgcn_s_setprio(0);
        }
        __builtin_amdgcn_s_barrier();    // end-of-tile: all waves consumed cur before t+1 overwrites it

        cur = (cur == 2) ? 0 : cur + 1;
        tgt = (tgt == 2) ? 0 : tgt + 1;
    }

    // epilogue: gelu(g)*u*w -> bf16
    unsigned short* actp = act + (size_t)p * (SQ * ID);
    const int rb = mt * 128 + wr * 64 + ((lane >> 4) << 2);
    const int cb = nt * 128 + wc * 32 + (lane & 15);
#pragma unroll
    for (int mf = 0; mf < 4; ++mf)
#pragma unroll
        for (int nf = 0; nf < 2; ++nf)
#pragma unroll
            for (int r = 0; r < 4; ++r) {
                float g = accg[mf][nf][r];
                float u = accu[mf][nf][r];
                float tt = 0.7978845608028654f * (g + 0.044715f * g * g * g);
                float h = 0.5f * g * (1.0f + tanhf(tt)) * u * wS;
                actp[(size_t)(rb + mf * 16 + r) * ID + cb + nf * 16] = f2bf(h);
            }
}

// =====================================================================
// stage2: out = sum_slot act_slot @ down_slot  (fp32 out)
// Same pipelined skeleton: tile M128 x N256, BK=64, K = 3*4096.
// Grid = 4*2*32 = 256 blocks = exactly 1 per CU.
// =====================================================================
__global__ __launch_bounds__(512, 2) void stage2_down(
    const unsigned short* __restrict__ act,     // [96][256][4096]
    const unsigned short* __restrict__ downT,   // [9][1024][4096]
    const int* __restrict__ eid,
    float* __restrict__ out)                    // [32][256][1024]
{
    extern __shared__ unsigned short lds[];     // 3 bufs * 24576 shorts

    const int lid = blockIdx.x;
    const int swz = (lid & 7) * 32 + (lid >> 3);   // 256 = 8 * 32
    const int nt  = swz & 3;           // H tile (256 wide)
    const int mt  = (swz >> 2) & 1;    // token tile
    const int b   = swz >> 3;          // batch
    const int b3  = b * 3;
    const int e0 = eid[b3], e1 = eid[b3 + 1], e2 = eid[b3 + 2];

    const int tid  = threadIdx.x;
    const int wv   = tid >> 6;
    const int lane = tid & 63;
    const int wr   = wv >> 2;          // 0..1
    const int wc   = wv & 3;           // 0..3

    const int lhi  = lane >> 3;
    const int llo  = lane & 7;
    const int csw8 = (llo ^ lhi) * 8;
    const int w2   = wv * 2, w4 = wv * 4;

    const size_t laneA = (size_t)(wv * 16 + lhi) * ID + csw8;   // A: 16 segs, wave gets 2
    const size_t laneB = (size_t)(wv * 32 + lhi) * ID + csw8;   // B: 32 segs, wave gets 4

    const int lrow = lane & 15;
    const int kq   = (lane >> 4) * 8;
    const int xt   = (lrow & 7) << 3;
    const int c0s  = kq ^ xt;
    const int c1s  = (32 + kq) ^ xt;
    const int rA0  = (wr * 64 + lrow) * 64;
    const int rB0  = (wc * 64 + lrow) * 64;

    f32x4 acc[4][4];
#pragma unroll
    for (int i = 0; i < 4; ++i)
#pragma unroll
        for (int j = 0; j < 4; ++j) acc[i][j] = (f32x4)0.f;

    const int NT = 3 * ID / 64;   // 192 K-tiles

    auto srcAB = [&](int tt, const unsigned short*& A, const unsigned short*& B) {
        const int slot = tt >> 6;
        const int i0   = (tt & 63) << 6;
        const int esl  = (slot == 0) ? e0 : ((slot == 1) ? e1 : e2);
        A = act   + ((size_t)(b3 + slot) * SQ + mt * 128) * ID + i0 + laneA;
        B = downT + ((size_t)esl * HD + nt * 256) * ID + i0 + laneB;
    };

    // prologue: tiles 0,1 -> bufs 0,1
#pragma unroll
    for (int t0 = 0; t0 < 2; ++t0) {
        const unsigned short *A, *B;
        srcAB(t0, A, B);
        unsigned short* Lb = lds + t0 * 24576;
#pragma unroll
        for (int q = 0; q < 2; ++q)
            gld_lds16(A + (size_t)q * (8 * ID), Lb + (w2 + q) * 512);
#pragma unroll
        for (int q = 0; q < 4; ++q)
            gld_lds16(B + (size_t)q * (8 * ID), Lb + 8192 + (w4 + q) * 512);
    }

    int cur = 0, tgt = 2;
#pragma unroll 1
    for (int t = 0; t < NT; ++t) {
        __builtin_amdgcn_sched_barrier(0);
        unsigned short* Lc = lds + cur * 24576;
        unsigned short* Lt = lds + tgt * 24576;
        const bool pf = (t + 2 < NT);
        const unsigned short *SA = nullptr, *SB = nullptr;
        if (pf) {
            srcAB(t + 2, SA, SB);
            gld_lds16(SA,                    Lt +        w2 * 512);
            gld_lds16(SA + (size_t)(8 * ID), Lt +        (w2 + 1) * 512);
            gld_lds16(SB,                    Lt + 8192 + w4 * 512);
            WAITVM(9);
        } else if (t + 1 < NT) {
            WAITVM(6);
        } else {
            WAITVM(0);
        }
        __builtin_amdgcn_s_barrier();
        __builtin_amdgcn_sched_barrier(0);

        // ---- phase 1: kk = 0 ----
        {
            bf16x8 af[4], bfr[4];
#pragma unroll
            for (int mf = 0; mf < 4; ++mf)
                af[mf] = *(const bf16x8*)(Lc + rA0 + mf * 1024 + c0s);
#pragma unroll
            for (int nf = 0; nf < 4; ++nf)
                bfr[nf] = *(const bf16x8*)(Lc + 8192 + rB0 + nf * 1024 + c0s);
            __builtin_amdgcn_s_setprio(1);
#pragma unroll
            for (int mf = 0; mf < 4; ++mf)
#pragma unroll
                for (int nf = 0; nf < 4; ++nf)
                    acc[mf][nf] = __builtin_amdgcn_mfma_f32_16x16x32_bf16(af[mf], bfr[nf], acc[mf][nf], 0, 0, 0);
            __builtin_amdgcn_s_setprio(0);
        }
        __builtin_amdgcn_s_barrier();

        // ---- phase 2: kk = 32 (+ B q1..q3 prefetch) ----
        {
            bf16x8 af[4], bfr[4];
#pragma unroll
            for (int mf = 0; mf < 4; ++mf)
                af[mf] = *(const bf16x8*)(Lc + rA0 + mf * 1024 + c1s);
#pragma unroll
            for (int nf = 0; nf < 4; ++nf)
                bfr[nf] = *(const bf16x8*)(Lc + 8192 + rB0 + nf * 1024 + c1s);
            if (pf) {
                gld_lds16(SB + (size_t)(8  * ID), Lt + 8192 + (w4 + 1) * 512);
                gld_lds16(SB + (size_t)(16 * ID), Lt + 8192 + (w4 + 2) * 512);
                gld_lds16(SB + (size_t)(24 * ID), Lt + 8192 + (w4 + 3) * 512);
            }
            __builtin_amdgcn_s_setprio(1);
#pragma unroll
            for (int mf = 0; mf < 4; ++mf)
#pragma unroll
                for (int nf = 0; nf < 4; ++nf)
                    acc[mf][nf] = __builtin_amdgcn_mfma_f32_16x16x32_bf16(af[mf], bfr[nf], acc[mf][nf], 0, 0, 0);
            __builtin_amdgcn_s_setprio(0);
        }
        __builtin_amdgcn_s_barrier();

        cur = (cur == 2) ? 0 : cur + 1;
        tgt = (tgt == 2) ? 0 : tgt + 1;
    }

    const int rb  = mt * 128 + wr * 64 + ((lane >> 4) << 2);
    const int cbN = nt * 256 + wc * 64 + (lane & 15);
#pragma unroll
    for (int mf = 0; mf < 4; ++mf)
#pragma unroll
        for (int nf = 0; nf < 4; ++nf)
#pragma unroll
            for (int r = 0; r < 4; ++r)
                out[((size_t)b * SQ + rb + mf * 16 + r) * HD + cbN + nf * 16] = acc[mf][nf][r];
}

// ---------------- host ----------------
extern "C" void kernel_launch(void* const* d_in, const int* in_sizes, int n_in,
                              void* d_out, int out_size, void* d_ws, size_t ws_size,
                              hipStream_t stream) {
    const float* x        = (const float*)d_in[0];
    const float* logits   = (const float*)d_in[1];
    const float* sk_gate  = (const float*)d_in[2];
    const float* sk_up    = (const float*)d_in[3];
    const float* sk_down  = (const float*)d_in[4];
    const float* sh_gate  = (const float*)d_in[5];
    const float* sh_up    = (const float*)d_in[6];
    const float* sh_down  = (const float*)d_in[7];
    float* out = (float*)d_out;

    char* ws = (char*)d_ws;
    int*            eid   = (int*)(ws + OFF_EID);
    float*          wgt   = (float*)(ws + OFF_WGT);
    unsigned short* xbf   = (unsigned short*)(ws + OFF_XBF);
    unsigned short* gateT = (unsigned short*)(ws + OFF_GATET);
    unsigned short* upT   = (unsigned short*)(ws + OFF_UPT);
    unsigned short* downT = (unsigned short*)(ws + OFF_DOWNT);
    unsigned short* act   = (unsigned short*)(ws + OFF_ACT);

    static int attr_set = 0;
    if (!attr_set) {
        hipFuncSetAttribute(reinterpret_cast<const void*>(stage1_gateup),
                            hipFuncAttributeMaxDynamicSharedMemorySize, 147456);
        hipFuncSetAttribute(reinterpret_cast<const void*>(stage2_down),
                            hipFuncAttributeMaxDynamicSharedMemorySize, 147456);
        attr_set = 1;
    }

    routing_kernel<<<1, 64, 0, stream>>>(logits, eid, wgt);

    const int n4 = (NB * SQ * HD) / 4;
    xcvt_kernel<<<(n4 + 255) / 256, 256, 0, stream>>>(x, xbf, n4);

    // gate/up: [1024][4096] -> [4096][1024];  down: [4096][1024] -> [1024][4096]
    transpose_cvt<<<dim3(ID / 64, HD / 64, 9), 256, 0, stream>>>(sk_gate, sh_gate, gateT, HD, ID);
    transpose_cvt<<<dim3(ID / 64, HD / 64, 9), 256, 0, stream>>>(sk_up,   sh_up,   upT,   HD, ID);
    transpose_cvt<<<dim3(HD / 64, ID / 64, 9), 256, 0, stream>>>(sk_down, sh_down, downT, ID, HD);

    stage1_gateup<<<dim3(PAIRS * 64), 512, 147456, stream>>>(xbf, gateT, upT, eid, wgt, act);
    stage2_down<<<dim3(256), 512, 147456, stream>>>(act, downT, eid, out);
}

// Round 2
// 1121.911 us; speedup vs baseline: 1.1650x; 1.0762x over previous
//
#include <hip/hip_runtime.h>

// ---------------- types & helpers ----------------
typedef __bf16 bf16x8 __attribute__((ext_vector_type(8)));
typedef float  f32x4  __attribute__((ext_vector_type(4)));

__device__ __forceinline__ unsigned short f2bf(float f) {
    unsigned u = __float_as_uint(f);
    u += 0x7fffu + ((u >> 16) & 1u);   // RNE
    return (unsigned short)(u >> 16);
}

__device__ __forceinline__ void gld_lds16(const void* g, void* l) {
    __builtin_amdgcn_global_load_lds(
        (const __attribute__((address_space(1))) void*)g,
        (__attribute__((address_space(3))) void*)l,
        16, 0, 0);
}

#define WAITVM(N) asm volatile("s_waitcnt vmcnt(" #N ")" ::: "memory")

// ---------------- problem constants ----------------
#define NB  32
#define SQ  256
#define HD  1024
#define ID  4096
#define NEXP 8          // skill experts; index 8 = shared
#define PAIRS (NB * 3)  // (batch, slot) pairs

// workspace layout (bytes)
#define OFF_EID    ((size_t)0)            // 96 int
#define OFF_WGT    ((size_t)512)          // 96 float
#define OFF_XBF    ((size_t)1024)                       // 8192*1024 bf16
#define OFF_GATET  (OFF_XBF   + (size_t)16777216)       // 9*4096*1024 bf16
#define OFF_UPT    (OFF_GATET + (size_t)75497472)
#define OFF_DOWNT  (OFF_UPT   + (size_t)75497472)
#define OFF_ACT    (OFF_DOWNT + (size_t)75497472)       // 96*256*4096 bf16

// pair order sorted by expert id (locality for weight reuse)
__device__ int d_sord[PAIRS];

// ---------------- routing ----------------
__global__ void routing_kernel(const float* __restrict__ logits,
                               int* __restrict__ eid, float* __restrict__ wgt) {
    int b = threadIdx.x;
    if (b < NB) {
        float l[NEXP];
        for (int j = 0; j < NEXP; ++j) l[j] = logits[b * NEXP + j];
        int a0 = 0;
        for (int j = 1; j < NEXP; ++j) if (l[j] > l[a0]) a0 = j;
        int a1 = -1;
        for (int j = 0; j < NEXP; ++j) {
            if (j == a0) continue;
            if (a1 < 0 || l[j] > l[a1]) a1 = j;
        }
        float w0 = 1.0f / (1.0f + expf(l[a1] - l[a0]));
        eid[b * 3 + 0] = a0;  wgt[b * 3 + 0] = w0;
        eid[b * 3 + 1] = a1;  wgt[b * 3 + 1] = 1.0f - w0;
        eid[b * 3 + 2] = NEXP; wgt[b * 3 + 2] = 1.0f;   // shared
    }
    __syncthreads();
    if (threadIdx.x == 0) {
        // counting sort of the 96 pairs by expert id (stable)
        int cnt[NEXP + 2];
        for (int i = 0; i < NEXP + 2; ++i) cnt[i] = 0;
        for (int i = 0; i < PAIRS; ++i) cnt[eid[i] + 1]++;
        for (int e = 0; e < NEXP + 1; ++e) cnt[e + 1] += cnt[e];
        for (int i = 0; i < PAIRS; ++i) d_sord[cnt[eid[i]]++] = i;
    }
}

// ---------------- x fp32 -> bf16 ----------------
__global__ void xcvt_kernel(const float* __restrict__ x,
                            unsigned short* __restrict__ xb, int n4) {
    int i = blockIdx.x * 256 + threadIdx.x;
    if (i < n4) {
        float4 v = ((const float4*)x)[i];
        union { unsigned short s[4]; uint2 u; } p;
        p.s[0] = f2bf(v.x); p.s[1] = f2bf(v.y);
        p.s[2] = f2bf(v.z); p.s[3] = f2bf(v.w);
        ((uint2*)xb)[i] = p.u;
    }
}

// ---------------- weight transpose+convert: [R][C] fp32 -> [C][R] bf16 ----------------
__global__ void transpose_cvt(const float* __restrict__ skill,
                              const float* __restrict__ shared_m,
                              unsigned short* __restrict__ out, int R, int C) {
    const int e = blockIdx.z;                       // 0..8
    const float* src = (e < NEXP) ? (skill + (size_t)e * R * C) : shared_m;
    unsigned short* dst = out + (size_t)e * R * C;  // [C][R]
    const int c0 = blockIdx.x * 64;
    const int r0 = blockIdx.y * 64;
    __shared__ unsigned short t[64][66];
    const int tid = threadIdx.x;
    const int lr = tid >> 4;            // 0..15
    const int lc = (tid & 15) * 4;
    for (int it = 0; it < 4; ++it) {
        int r = lr + it * 16;
        float4 v = *(const float4*)(src + (size_t)(r0 + r) * C + c0 + lc);
        t[r][lc + 0] = f2bf(v.x);
        t[r][lc + 1] = f2bf(v.y);
        t[r][lc + 2] = f2bf(v.z);
        t[r][lc + 3] = f2bf(v.w);
    }
    __syncthreads();
    const int oc = tid >> 2;            // out row (original col), 0..63
    const int k0 = (tid & 3) * 16;      // 16 elems along original rows
    unsigned int pk[8];
    for (int j = 0; j < 8; ++j) {
        unsigned int lo = t[k0 + 2 * j + 0][oc];
        unsigned int hi = t[k0 + 2 * j + 1][oc];
        pk[j] = lo | (hi << 16);
    }
    unsigned short* dp = dst + (size_t)(c0 + oc) * R + r0 + k0;
    ((uint4*)dp)[0] = make_uint4(pk[0], pk[1], pk[2], pk[3]);
    ((uint4*)dp)[1] = make_uint4(pk[4], pk[5], pk[6], pk[7]);
}

// =====================================================================
// stage1: act = gelu(x@gate) * (x@up) * w  (bf16 out)
// 512 thr / 8 waves, tile M128 x N128(gate)+N128(up), BK=64.
// Triple-buffered LDS, counted vmcnt, 2 phases/K-tile, swizzled LDS.
// Block order: XCD g owns 12 expert-sorted pairs; subgroups of 4 pairs,
// nt outer / (pair,mt) inner -> weight tile + A tiles co-resident in L2.
// =====================================================================
__global__ __launch_bounds__(512, 2) void stage1_gateup(
    const unsigned short* __restrict__ xbf,     // [8192][1024]
    const unsigned short* __restrict__ gateT,   // [9][4096][1024]
    const unsigned short* __restrict__ upT,
    const int* __restrict__ eid, const float* __restrict__ wgt,
    unsigned short* __restrict__ act)           // [96][256][4096]
{
    extern __shared__ unsigned short lds[];     // 3 bufs * 24576 shorts (144 KiB)

    // locality mapping: bid -> (XCD g, subgroup sg, nt, pair-slot, mt)
    const int bid = blockIdx.x;
    const int g  = bid & 7;            // XCD (dispatch round-robin)
    const int r  = bid >> 3;           // 0..767 rank within XCD
    const int sg = r >> 8;             // 0..2   subgroup of 4 pairs
    const int rr = r & 255;
    const int nt = rr >> 3;            // 0..31  I tile (slow)
    const int q  = rr & 7;
    const int j  = g * 12 + sg * 4 + (q >> 1);  // sorted-pair index 0..95
    const int mt = q & 1;              // token tile (fast)
    const int p  = d_sord[j];
    const int b  = p / 3;
    const int e  = eid[p];
    const float wS = wgt[p];

    const int tid  = threadIdx.x;
    const int wv   = tid >> 6;
    const int lane = tid & 63;
    const int wr   = wv >> 2;          // 0..1 : M half
    const int wc   = wv & 3;           // 0..3 : N quarter

    // staging lane geometry: seg = 8 rows x 64 cols (1 KiB)
    const int lhi  = lane >> 3;
    const int llo  = lane & 7;
    const int csw8 = (llo ^ lhi) * 8;  // pre-swizzled SOURCE chunk
    const int w2   = wv * 2;

    const size_t lofs = (size_t)(wv * 16 + lhi) * HD + csw8;
    const unsigned short* pA = xbf   + (size_t)(b * SQ + mt * 128) * HD + lofs;
    const unsigned short* pG = gateT + ((size_t)e * ID + nt * 128) * HD + lofs;
    const unsigned short* pU = upT   + ((size_t)e * ID + nt * 128) * HD + lofs;

    const int lrow = lane & 15;
    const int kq   = (lane >> 4) * 8;
    const int xt   = (lrow & 7) << 3;
    const int c0s  = kq ^ xt;          // phase 1 (kk=0)
    const int c1s  = (32 + kq) ^ xt;   // phase 2 (kk=32)
    const int rA0  = (wr * 64 + lrow) * 64;
    const int rG0  = (wc * 32 + lrow) * 64;

    f32x4 accg[4][2], accu[4][2];
#pragma unroll
    for (int i = 0; i < 4; ++i)
#pragma unroll
        for (int jj = 0; jj < 2; ++jj) { accg[i][jj] = (f32x4)0.f; accu[i][jj] = (f32x4)0.f; }

    const int NT = HD / 64;   // 16 K-tiles

    // prologue: stage tiles 0,1 into bufs 0,1
#pragma unroll
    for (int t0 = 0; t0 < 2; ++t0) {
        unsigned short* Lb = lds + t0 * 24576;
#pragma unroll
        for (int qq = 0; qq < 2; ++qq) {
            const size_t o = (size_t)t0 * 64 + (size_t)qq * (8 * HD);
            gld_lds16(pA + o, Lb +         (w2 + qq) * 512);
            gld_lds16(pG + o, Lb +  8192 + (w2 + qq) * 512);
            gld_lds16(pU + o, Lb + 16384 + (w2 + qq) * 512);
        }
    }

    int cur = 0, tgt = 2;
#pragma unroll 1
    for (int t = 0; t < NT; ++t) {
        __builtin_amdgcn_sched_barrier(0);
        unsigned short* Lc = lds + cur * 24576;
        unsigned short* Lt = lds + tgt * 24576;
        const bool pf = (t + 2 < NT);
        const size_t kp = (size_t)(t + 2) * 64;
        if (pf) {
            gld_lds16(pA + kp, Lt +         w2 * 512);
            gld_lds16(pG + kp, Lt +  8192 + w2 * 512);
            gld_lds16(pU + kp, Lt + 16384 + w2 * 512);
            WAITVM(9);
        } else if (t + 1 < NT) {
            WAITVM(6);
        } else {
            WAITVM(0);
        }
        __builtin_amdgcn_s_barrier();
        __builtin_amdgcn_sched_barrier(0);

        // ---- phase 1: kk = 0 ----
        {
            bf16x8 af[4], gf[2], uf[2];
#pragma unroll
            for (int mf = 0; mf < 4; ++mf)
                af[mf] = *(const bf16x8*)(Lc + rA0 + mf * 1024 + c0s);
#pragma unroll
            for (int nf = 0; nf < 2; ++nf) {
                gf[nf] = *(const bf16x8*)(Lc +  8192 + rG0 + nf * 1024 + c0s);
                uf[nf] = *(const bf16x8*)(Lc + 16384 + rG0 + nf * 1024 + c0s);
            }
            __builtin_amdgcn_s_setprio(1);
#pragma unroll
            for (int mf = 0; mf < 4; ++mf)
#pragma unroll
                for (int nf = 0; nf < 2; ++nf) {
                    accg[mf][nf] = __builtin_amdgcn_mfma_f32_16x16x32_bf16(af[mf], gf[nf], accg[mf][nf], 0, 0, 0);
                    accu[mf][nf] = __builtin_amdgcn_mfma_f32_16x16x32_bf16(af[mf], uf[nf], accu[mf][nf], 0, 0, 0);
                }
            __builtin_amdgcn_s_setprio(0);
        }
        __builtin_amdgcn_s_barrier();

        // ---- phase 2: kk = 32 (+ second half of prefetch) ----
        {
            bf16x8 af[4], gf[2], uf[2];
#pragma unroll
            for (int mf = 0; mf < 4; ++mf)
                af[mf] = *(const bf16x8*)(Lc + rA0 + mf * 1024 + c1s);
#pragma unroll
            for (int nf = 0; nf < 2; ++nf) {
                gf[nf] = *(const bf16x8*)(Lc +  8192 + rG0 + nf * 1024 + c1s);
                uf[nf] = *(const bf16x8*)(Lc + 16384 + rG0 + nf * 1024 + c1s);
            }
            if (pf) {
                gld_lds16(pA + kp + 8 * HD, Lt +         (w2 + 1) * 512);
                gld_lds16(pG + kp + 8 * HD, Lt +  8192 + (w2 + 1) * 512);
                gld_lds16(pU + kp + 8 * HD, Lt + 16384 + (w2 + 1) * 512);
            }
            __builtin_amdgcn_s_setprio(1);
#pragma unroll
            for (int mf = 0; mf < 4; ++mf)
#pragma unroll
                for (int nf = 0; nf < 2; ++nf) {
                    accg[mf][nf] = __builtin_amdgcn_mfma_f32_16x16x32_bf16(af[mf], gf[nf], accg[mf][nf], 0, 0, 0);
                    accu[mf][nf] = __builtin_amdgcn_mfma_f32_16x16x32_bf16(af[mf], uf[nf], accu[mf][nf], 0, 0, 0);
                }
            __builtin_amdgcn_s_setprio(0);
        }
        __builtin_amdgcn_s_barrier();

        cur = (cur == 2) ? 0 : cur + 1;
        tgt = (tgt == 2) ? 0 : tgt + 1;
    }

    // epilogue: gelu(g)*u*w -> bf16   (exp-based tanh identity, ~11 VALU/val)
    unsigned short* actp = act + (size_t)p * (SQ * ID);
    const int rb = mt * 128 + wr * 64 + ((lane >> 4) << 2);
    const int cb = nt * 128 + wc * 32 + (lane & 15);
#pragma unroll
    for (int mf = 0; mf < 4; ++mf)
#pragma unroll
        for (int nf = 0; nf < 2; ++nf)
#pragma unroll
            for (int r2 = 0; r2 < 4; ++r2) {
                float gv = accg[mf][nf][r2];
                float uv = accu[mf][nf][r2];
                // gelu_tanh(g) = g * sigmoid(2*0.79788456*(g + 0.044715 g^3))
                float t2 = -1.5957691216057308f * gv * (1.0f + 0.044715f * gv * gv);
                float h  = __fdividef(gv, 1.0f + __expf(t2)) * uv * wS;
                actp[(size_t)(rb + mf * 16 + r2) * ID + cb + nf * 16] = f2bf(h);
            }
}

// =====================================================================
// stage2: out = sum_slot act_slot @ down_slot  (fp32 out)
// =====================================================================
__global__ __launch_bounds__(512, 2) void stage2_down(
    const unsigned short* __restrict__ act,     // [96][256][4096]
    const unsigned short* __restrict__ downT,   // [9][1024][4096]
    const int* __restrict__ eid,
    float* __restrict__ out)                    // [32][256][1024]
{
    extern __shared__ unsigned short lds[];     // 3 bufs * 24576 shorts

    const int lid = blockIdx.x;
    const int swz = (lid & 7) * 32 + (lid >> 3);   // 256 = 8 * 32
    const int nt  = swz & 3;           // H tile (256 wide)
    const int mt  = (swz >> 2) & 1;    // token tile
    const int b   = swz >> 3;          // batch
    const int b3  = b * 3;
    const int e0 = eid[b3], e1 = eid[b3 + 1], e2 = eid[b3 + 2];

    const int tid  = threadIdx.x;
    const int wv   = tid >> 6;
    const int lane = tid & 63;
    const int wr   = wv >> 2;          // 0..1
    const int wc   = wv & 3;           // 0..3

    const int lhi  = lane >> 3;
    const int llo  = lane & 7;
    const int csw8 = (llo ^ lhi) * 8;
    const int w2   = wv * 2, w4 = wv * 4;

    const size_t laneA = (size_t)(wv * 16 + lhi) * ID + csw8;
    const size_t laneB = (size_t)(wv * 32 + lhi) * ID + csw8;

    const int lrow = lane & 15;
    const int kq   = (lane >> 4) * 8;
    const int xt   = (lrow & 7) << 3;
    const int c0s  = kq ^ xt;
    const int c1s  = (32 + kq) ^ xt;
    const int rA0  = (wr * 64 + lrow) * 64;
    const int rB0  = (wc * 64 + lrow) * 64;

    f32x4 acc[4][4];
#pragma unroll
    for (int i = 0; i < 4; ++i)
#pragma unroll
        for (int j = 0; j < 4; ++j) acc[i][j] = (f32x4)0.f;

    const int NT = 3 * ID / 64;   // 192 K-tiles

    auto srcAB = [&](int tt, const unsigned short*& A, const unsigned short*& B) {
        const int slot = tt >> 6;
        const int i0   = (tt & 63) << 6;
        const int esl  = (slot == 0) ? e0 : ((slot == 1) ? e1 : e2);
        A = act   + ((size_t)(b3 + slot) * SQ + mt * 128) * ID + i0 + laneA;
        B = downT + ((size_t)esl * HD + nt * 256) * ID + i0 + laneB;
    };

    // prologue: tiles 0,1 -> bufs 0,1
#pragma unroll
    for (int t0 = 0; t0 < 2; ++t0) {
        const unsigned short *A, *B;
        srcAB(t0, A, B);
        unsigned short* Lb = lds + t0 * 24576;
#pragma unroll
        for (int q = 0; q < 2; ++q)
            gld_lds16(A + (size_t)q * (8 * ID), Lb + (w2 + q) * 512);
#pragma unroll
        for (int q = 0; q < 4; ++q)
            gld_lds16(B + (size_t)q * (8 * ID), Lb + 8192 + (w4 + q) * 512);
    }

    int cur = 0, tgt = 2;
#pragma unroll 1
    for (int t = 0; t < NT; ++t) {
        __builtin_amdgcn_sched_barrier(0);
        unsigned short* Lc = lds + cur * 24576;
        unsigned short* Lt = lds + tgt * 24576;
        const bool pf = (t + 2 < NT);
        const unsigned short *SA = nullptr, *SB = nullptr;
        if (pf) {
            srcAB(t + 2, SA, SB);
            gld_lds16(SA,                    Lt +        w2 * 512);
            gld_lds16(SA + (size_t)(8 * ID), Lt +        (w2 + 1) * 512);
            gld_lds16(SB,                    Lt + 8192 + w4 * 512);
            WAITVM(9);
        } else if (t + 1 < NT) {
            WAITVM(6);
        } else {
            WAITVM(0);
        }
        __builtin_amdgcn_s_barrier();
        __builtin_amdgcn_sched_barrier(0);

        // ---- phase 1: kk = 0 ----
        {
            bf16x8 af[4], bfr[4];
#pragma unroll
            for (int mf = 0; mf < 4; ++mf)
                af[mf] = *(const bf16x8*)(Lc + rA0 + mf * 1024 + c0s);
#pragma unroll
            for (int nf = 0; nf < 4; ++nf)
                bfr[nf] = *(const bf16x8*)(Lc + 8192 + rB0 + nf * 1024 + c0s);
            __builtin_amdgcn_s_setprio(1);
#pragma unroll
            for (int mf = 0; mf < 4; ++mf)
#pragma unroll
                for (int nf = 0; nf < 4; ++nf)
                    acc[mf][nf] = __builtin_amdgcn_mfma_f32_16x16x32_bf16(af[mf], bfr[nf], acc[mf][nf], 0, 0, 0);
            __builtin_amdgcn_s_setprio(0);
        }
        __builtin_amdgcn_s_barrier();

        // ---- phase 2: kk = 32 (+ B q1..q3 prefetch) ----
        {
            bf16x8 af[4], bfr[4];
#pragma unroll
            for (int mf = 0; mf < 4; ++mf)
                af[mf] = *(const bf16x8*)(Lc + rA0 + mf * 1024 + c1s);
#pragma unroll
            for (int nf = 0; nf < 4; ++nf)
                bfr[nf] = *(const bf16x8*)(Lc + 8192 + rB0 + nf * 1024 + c1s);
            if (pf) {
                gld_lds16(SB + (size_t)(8  * ID), Lt + 8192 + (w4 + 1) * 512);
                gld_lds16(SB + (size_t)(16 * ID), Lt + 8192 + (w4 + 2) * 512);
                gld_lds16(SB + (size_t)(24 * ID), Lt + 8192 + (w4 + 3) * 512);
            }
            __builtin_amdgcn_s_setprio(1);
#pragma unroll
            for (int mf = 0; mf < 4; ++mf)
#pragma unroll
                for (int nf = 0; nf < 4; ++nf)
                    acc[mf][nf] = __builtin_amdgcn_mfma_f32_16x16x32_bf16(af[mf], bfr[nf], acc[mf][nf], 0, 0, 0);
            __builtin_amdgcn_s_setprio(0);
        }
        __builtin_amdgcn_s_barrier();

        cur = (cur == 2) ? 0 : cur + 1;
        tgt = (tgt == 2) ? 0 : tgt + 1;
    }

    const int rb  = mt * 128 + wr * 64 + ((lane >> 4) << 2);
    const int cbN = nt * 256 + wc * 64 + (lane & 15);
#pragma unroll
    for (int mf = 0; mf < 4; ++mf)
#pragma unroll
        for (int nf = 0; nf < 4; ++nf)
#pragma unroll
            for (int r = 0; r < 4; ++r)
                out[((size_t)b * SQ + rb + mf * 16 + r) * HD + cbN + nf * 16] = acc[mf][nf][r];
}

// ---------------- host ----------------
extern "C" void kernel_launch(void* const* d_in, const int* in_sizes, int n_in,
                              void* d_out, int out_size, void* d_ws, size_t ws_size,
                              hipStream_t stream) {
    const float* x        = (const float*)d_in[0];
    const float* logits   = (const float*)d_in[1];
    const float* sk_gate  = (const float*)d_in[2];
    const float* sk_up    = (const float*)d_in[3];
    const float* sk_down  = (const float*)d_in[4];
    const float* sh_gate  = (const float*)d_in[5];
    const float* sh_up    = (const float*)d_in[6];
    const float* sh_down  = (const float*)d_in[7];
    float* out = (float*)d_out;

    char* ws = (char*)d_ws;
    int*            eid   = (int*)(ws + OFF_EID);
    float*          wgt   = (float*)(ws + OFF_WGT);
    unsigned short* xbf   = (unsigned short*)(ws + OFF_XBF);
    unsigned short* gateT = (unsigned short*)(ws + OFF_GATET);
    unsigned short* upT   = (unsigned short*)(ws + OFF_UPT);
    unsigned short* downT = (unsigned short*)(ws + OFF_DOWNT);
    unsigned short* act   = (unsigned short*)(ws + OFF_ACT);

    static int attr_set = 0;
    if (!attr_set) {
        hipFuncSetAttribute(reinterpret_cast<const void*>(stage1_gateup),
                            hipFuncAttributeMaxDynamicSharedMemorySize, 147456);
        hipFuncSetAttribute(reinterpret_cast<const void*>(stage2_down),
                            hipFuncAttributeMaxDynamicSharedMemorySize, 147456);
        attr_set = 1;
    }

    routing_kernel<<<1, 64, 0, stream>>>(logits, eid, wgt);

    const int n4 = (NB * SQ * HD) / 4;
    xcvt_kernel<<<(n4 + 255) / 256, 256, 0, stream>>>(x, xbf, n4);

    // gate/up: [1024][4096] -> [4096][1024];  down: [4096][1024] -> [1024][4096]
    transpose_cvt<<<dim3(ID / 64, HD / 64, 9), 256, 0, stream>>>(sk_gate, sh_gate, gateT, HD, ID);
    transpose_cvt<<<dim3(ID / 64, HD / 64, 9), 256, 0, stream>>>(sk_up,   sh_up,   upT,   HD, ID);
    transpose_cvt<<<dim3(HD / 64, ID / 64, 9), 256, 0, stream>>>(sk_down, sh_down, downT, ID, HD);

    stage1_gateup<<<dim3(PAIRS * 64), 512, 147456, stream>>>(xbf, gateT, upT, eid, wgt, act);
    stage2_down<<<dim3(256), 512, 147456, stream>>>(act, downT, eid, out);
}